// Round 8
// baseline (825.052 us; speedup 1.0000x reference)
//
#include <hip/hip_runtime.h>
#include <math.h>

typedef float f2v __attribute__((ext_vector_type(2)));
typedef float f4v __attribute__((ext_vector_type(4)));

#define FT 36864      // words per batch (4096 * 9)
#define NCHUNK 64     // chunks per batch; chunk = 64 f-rows = 576 words = 144 f4v

// lane = hg + 8*fs.  hg in 0..7: owns h-quad h = hg*4..hg*4+3.
//                    fs in 0..7: owns f-rows fs*8..fs*8+7 of each chunk.
// Lane's x slice per chunk: 72 consecutive words = 18 aligned f4v, with a
// STATIC t-pattern (word w -> t = w%9, row = w/9) since 72 % 9 == 0.
#define XW(w) xv[(w) >> 2][(w) & 3]

__global__ __launch_bounds__(256) void scorer_kernel(
    const float* __restrict__ x,     // [B, 4096, 9]
    const float* __restrict__ th1,   // [2]
    const float* __restrict__ W1,    // [4096, 32]
    const float* __restrict__ b1,    // [32]
    const float* __restrict__ gamma, // [32]
    const float* __restrict__ beta,  // [32]
    const float* __restrict__ th2,   // [2]
    const float* __restrict__ W2,    // [32]
    const float* __restrict__ b2p,   // [1]
    float* __restrict__ out)         // [B, 9]
{
    const int tid  = threadIdx.x;
    const int lane = tid & 63;
    const int wv   = tid >> 6;
    const int hg   = lane & 7;
    const int fs   = lane >> 3;
    const size_t batch = (size_t)blockIdx.x * 4 + wv;

    const f4v* __restrict__ xv4 = (const f4v*)(x + batch * FT);
    const f4v* __restrict__ w1v = (const f4v*)W1;   // row f: f4v index f*8 + hg

    const float c0 = cosf(th1[0]), s0 = sinf(th1[0]);
    const float c1 = cosf(th1[1]), s1 = sinf(th1[1]);

    f2v acc[9][2];   // [t][pair]: h = hg*4 + pair*2 + {0,1}
    #pragma unroll
    for (int t = 0; t < 9; ++t) {
        acc[t][0] = (f2v){0.f, 0.f};
        acc[t][1] = (f2v){0.f, 0.f};
    }

    for (int c = 0; c < NCHUNK; ++c) {
        // ---- load lane's 72 x-words (18 f4v; chunk stride 144 f4v) ----
        f4v xv[18];
        const int xbase = c * 144 + fs * 18;
        #pragma unroll
        for (int j = 0; j < 18; ++j)
            xv[j] = __builtin_nontemporal_load(&xv4[xbase + j]);
        f4v wr8[8];
        const int frow = c * 64 + fs * 8;
        #pragma unroll
        for (int r = 0; r < 8; ++r)
            wr8[r] = w1v[(size_t)(frow + r) * 8 + hg];

        // ---- fold plane_rotate(theta1) into rows 0..3 (chunk 0, fs 0) ----
        if (c == 0 && fs == 0) {
            #pragma unroll
            for (int t = 0; t < 9; ++t) {
                float a = XW(t), b = XW(9 + t);
                XW(t)     = c0 * a - s0 * b;
                XW(9 + t) = s0 * a + c0 * b;
                float a2 = XW(18 + t), b2 = XW(27 + t);
                XW(18 + t) = c1 * a2 - s1 * b2;
                XW(27 + t) = s1 * a2 + c1 * b2;
            }
        }

        // ---- 8 rows x 9 t x 4 h: 144 pk-fma, all-static indexing ----
        #pragma unroll
        for (int r = 0; r < 8; ++r) {
            f2v wlo = {wr8[r].x, wr8[r].y};
            f2v whi = {wr8[r].z, wr8[r].w};
            #pragma unroll
            for (int t = 0; t < 9; ++t) {
                const int w = r * 9 + t;
                float xs = XW(w);
                acc[t][0] += (f2v){xs, xs} * wlo;
                acc[t][1] += (f2v){xs, xs} * whi;
            }
        }
    }

    // ---- reduce over fs: butterfly xor {8,16,32} (hg bits untouched) ----
    #pragma unroll
    for (int t = 0; t < 9; ++t)
        #pragma unroll
        for (int p = 0; p < 2; ++p) {
            f2v v = acc[t][p];
            v.x += __shfl_xor(v.x, 8);  v.y += __shfl_xor(v.y, 8);
            v.x += __shfl_xor(v.x, 16); v.y += __shfl_xor(v.y, 16);
            v.x += __shfl_xor(v.x, 32); v.y += __shfl_xor(v.y, 32);
            acc[t][p] = v;
        }

    // ---- per-lane epilogue params for its h-quad ----
    const int h0 = hg * 4;
    float b1q[4], gq[4], bq[4], w2q[4];
    #pragma unroll
    for (int j = 0; j < 4; ++j) {
        b1q[j] = b1[h0 + j];
        gq[j]  = gamma[h0 + j];
        bq[j]  = beta[h0 + j];
        w2q[j] = W2[h0 + j];
    }
    // fold plane_rotate(theta2) into W2 (rotate(g) . W2 == g . R^T W2);
    // only h 0..3 are rotated -> only hg==0 lanes adjust.
    if (hg == 0) {
        const float c2 = cosf(th2[0]), s2 = sinf(th2[0]);
        const float c3 = cosf(th2[1]), s3 = sinf(th2[1]);
        float a = w2q[0], b = w2q[1];
        w2q[0] =  c2 * a + s2 * b;
        w2q[1] = -s2 * a + c2 * b;
        float a2 = w2q[2], b2 = w2q[3];
        w2q[2] =  c3 * a2 + s3 * b2;
        w2q[3] = -s3 * a2 + c3 * b2;
    }

    // ---- bias + modular phase norm + affine + W2 partial dot ----
    float sc[9];
    #pragma unroll
    for (int t = 0; t < 9; ++t) {
        float p = 0.f;
        #pragma unroll
        for (int j = 0; j < 4; ++j) {
            float v = acc[t][j >> 1][j & 1] + b1q[j];
            float wr = v - 7.0f * floorf(v / 7.0f + 0.5f);
            float g = gq[j] * wr + bq[j];
            p += g * w2q[j];
        }
        sc[t] = p;
    }

    // ---- reduce over hg: butterfly xor {1,2,4} -> all lanes hold scores ----
    #pragma unroll
    for (int t = 0; t < 9; ++t) {
        sc[t] += __shfl_xor(sc[t], 1);
        sc[t] += __shfl_xor(sc[t], 2);
        sc[t] += __shfl_xor(sc[t], 4);
        sc[t] += b2p[0];
    }

    // ---- softmax over t (in-register), lane 0 writes 9 outputs ----
    float m = sc[0];
    #pragma unroll
    for (int t = 1; t < 9; ++t) m = fmaxf(m, sc[t]);
    float e[9], den = 0.f;
    #pragma unroll
    for (int t = 0; t < 9; ++t) { e[t] = expf(sc[t] - m); den += e[t]; }
    if (lane == 0) {
        #pragma unroll
        for (int t = 0; t < 9; ++t)
            out[batch * 9 + t] = e[t] / den;
    }
}

extern "C" void kernel_launch(void* const* d_in, const int* in_sizes, int n_in,
                              void* d_out, int out_size, void* d_ws, size_t ws_size,
                              hipStream_t stream) {
    const float* x     = (const float*)d_in[0];
    const float* th1   = (const float*)d_in[1];
    const float* W1    = (const float*)d_in[2];
    const float* b1    = (const float*)d_in[3];
    const float* gamma = (const float*)d_in[4];
    const float* beta  = (const float*)d_in[5];
    const float* th2   = (const float*)d_in[6];
    const float* W2    = (const float*)d_in[7];
    const float* b2    = (const float*)d_in[8];
    float* out = (float*)d_out;

    const int B = in_sizes[0] / FT;   // 8192
    dim3 grid(B / 4), block(256);     // 1 wave per batch, 4 waves per block
    hipLaunchKernelGGL(scorer_kernel, grid, block, 0, stream,
                       x, th1, W1, b1, gamma, beta, th2, W2, b2, out);
}

// Round 9
// 413.679 us; speedup vs baseline: 1.9944x; 1.9944x over previous
//
#include <hip/hip_runtime.h>
#include <math.h>

typedef float f2v __attribute__((ext_vector_type(2)));
typedef float f4v __attribute__((ext_vector_type(4)));

#define FT 36864      // words per batch (4096 * 9)
#define NITER 64      // 64 f-rows per iteration (576 words = 144 f4v)

// lane = hd + 4*fs.  hd in 0..3: owns h-octet h = hd*8 .. hd*8+7.
//                    fs in 0..15: owns f-rows fs*4..fs*4+3 of each iter-chunk.
// Lane's x slice per iter: 36 consecutive words = 9 aligned f4v, with a
// STATIC t-pattern (word w -> t = w%9, row = w/9) since 36 % 9 == 0.

__global__ __launch_bounds__(256) void scorer_kernel(
    const float* __restrict__ x,     // [B, 4096, 9]
    const float* __restrict__ th1,   // [2]
    const float* __restrict__ W1,    // [4096, 32]
    const float* __restrict__ b1,    // [32]
    const float* __restrict__ gamma, // [32]
    const float* __restrict__ beta,  // [32]
    const float* __restrict__ th2,   // [2]
    const float* __restrict__ W2,    // [32]
    const float* __restrict__ b2p,   // [1]
    float* __restrict__ out)         // [B, 9]
{
    const int tid  = threadIdx.x;
    const int lane = tid & 63;
    const int wv   = tid >> 6;
    const int hd   = lane & 3;
    const int fs   = lane >> 2;
    const size_t batch = (size_t)blockIdx.x * 4 + wv;

    const f4v* __restrict__ xv4 = (const f4v*)(x + batch * FT);
    const f4v* __restrict__ w1v = (const f4v*)W1;   // row f: f4v idx f*8 + hd*2 + q

    const float c0 = cosf(th1[0]), s0 = sinf(th1[0]);
    const float c1 = cosf(th1[1]), s1 = sinf(th1[1]);

    f2v acc[9][4];   // [t][q]: h = hd*8 + q*2 + {0,1}
    #pragma unroll
    for (int t = 0; t < 9; ++t)
        #pragma unroll
        for (int q = 0; q < 4; ++q) acc[t][q] = (f2v){0.f, 0.f};

    for (int it = 0; it < NITER; ++it) {
        // ---- lane's 36 x-words (9 f4v, DISTINCT per fs; cached loads) ----
        f4v xv[9];
        const int xbase = it * 144 + fs * 9;
        #pragma unroll
        for (int j = 0; j < 9; ++j) xv[j] = xv4[xbase + j];

        // ---- W1 for rows fs*4..fs*4+3, h-octet hd: 2 f4v per row ----
        f4v w1r[8];
        const int frow = it * 64 + fs * 4;
        #pragma unroll
        for (int r = 0; r < 4; ++r) {
            w1r[r * 2]     = w1v[(size_t)(frow + r) * 8 + hd * 2];
            w1r[r * 2 + 1] = w1v[(size_t)(frow + r) * 8 + hd * 2 + 1];
        }

        // ---- fold plane_rotate(theta1) into rows 0..3 (it 0, fs 0) ----
        if (it == 0 && fs == 0) {
            #pragma unroll
            for (int t = 0; t < 9; ++t) {
                // rows 0,1 = words t, 9+t ; rows 2,3 = words 18+t, 27+t
                float a = xv[t >> 2][t & 3], b = xv[(9 + t) >> 2][(9 + t) & 3];
                xv[t >> 2][t & 3]             = c0 * a - s0 * b;
                xv[(9 + t) >> 2][(9 + t) & 3] = s0 * a + c0 * b;
                float a2 = xv[(18 + t) >> 2][(18 + t) & 3];
                float b2 = xv[(27 + t) >> 2][(27 + t) & 3];
                xv[(18 + t) >> 2][(18 + t) & 3] = c1 * a2 - s1 * b2;
                xv[(27 + t) >> 2][(27 + t) & 3] = s1 * a2 + c1 * b2;
            }
        }

        // ---- 36 words x 8 h = 144 pk-fma, all-static indexing ----
        #pragma unroll
        for (int j = 0; j < 9; ++j) {
            #pragma unroll
            for (int k = 0; k < 4; ++k) {
                const int w = j * 4 + k;
                const int row = w / 9, t = w % 9;
                float xs = xv[j][k];
                f2v xs2 = {xs, xs};
                acc[t][0] += xs2 * (f2v){w1r[row * 2].x, w1r[row * 2].y};
                acc[t][1] += xs2 * (f2v){w1r[row * 2].z, w1r[row * 2].w};
                acc[t][2] += xs2 * (f2v){w1r[row * 2 + 1].x, w1r[row * 2 + 1].y};
                acc[t][3] += xs2 * (f2v){w1r[row * 2 + 1].z, w1r[row * 2 + 1].w};
            }
        }
    }

    // ---- reduce over fs: butterfly xor {4,8,16,32} (hd bits untouched) ----
    #pragma unroll
    for (int t = 0; t < 9; ++t)
        #pragma unroll
        for (int q = 0; q < 4; ++q) {
            f2v v = acc[t][q];
            v.x += __shfl_xor(v.x, 4);  v.y += __shfl_xor(v.y, 4);
            v.x += __shfl_xor(v.x, 8);  v.y += __shfl_xor(v.y, 8);
            v.x += __shfl_xor(v.x, 16); v.y += __shfl_xor(v.y, 16);
            v.x += __shfl_xor(v.x, 32); v.y += __shfl_xor(v.y, 32);
            acc[t][q] = v;
        }

    // ---- per-lane epilogue params for its h-octet ----
    const int h0 = hd * 8;
    float b1q[8], gq[8], bq[8], w2q[8];
    #pragma unroll
    for (int j = 0; j < 8; ++j) {
        b1q[j] = b1[h0 + j];
        gq[j]  = gamma[h0 + j];
        bq[j]  = beta[h0 + j];
        w2q[j] = W2[h0 + j];
    }
    // fold plane_rotate(theta2) into W2 (rotate(g).W2 == g.(R^T W2));
    // only h 0..3 rotated -> only hd==0 lanes adjust.
    if (hd == 0) {
        const float c2 = cosf(th2[0]), s2 = sinf(th2[0]);
        const float c3 = cosf(th2[1]), s3 = sinf(th2[1]);
        float a = w2q[0], b = w2q[1];
        w2q[0] =  c2 * a + s2 * b;
        w2q[1] = -s2 * a + c2 * b;
        float a2 = w2q[2], b2 = w2q[3];
        w2q[2] =  c3 * a2 + s3 * b2;
        w2q[3] = -s3 * a2 + c3 * b2;
    }

    // ---- bias + modular phase norm + affine + W2 partial dot ----
    float sc[9];
    #pragma unroll
    for (int t = 0; t < 9; ++t) {
        float p = 0.f;
        #pragma unroll
        for (int j = 0; j < 8; ++j) {
            float v = acc[t][j >> 1][j & 1] + b1q[j];
            float wr = v - 7.0f * floorf(v / 7.0f + 0.5f);
            float g = gq[j] * wr + bq[j];
            p += g * w2q[j];
        }
        sc[t] = p;
    }

    // ---- reduce over hd: butterfly xor {1,2} -> all lanes hold scores ----
    #pragma unroll
    for (int t = 0; t < 9; ++t) {
        sc[t] += __shfl_xor(sc[t], 1);
        sc[t] += __shfl_xor(sc[t], 2);
        sc[t] += b2p[0];
    }

    // ---- softmax over t (in-register), lane 0 writes 9 outputs ----
    float m = sc[0];
    #pragma unroll
    for (int t = 1; t < 9; ++t) m = fmaxf(m, sc[t]);
    float e[9], den = 0.f;
    #pragma unroll
    for (int t = 0; t < 9; ++t) { e[t] = expf(sc[t] - m); den += e[t]; }
    if (lane == 0) {
        #pragma unroll
        for (int t = 0; t < 9; ++t)
            out[batch * 9 + t] = e[t] / den;
    }
}

extern "C" void kernel_launch(void* const* d_in, const int* in_sizes, int n_in,
                              void* d_out, int out_size, void* d_ws, size_t ws_size,
                              hipStream_t stream) {
    const float* x     = (const float*)d_in[0];
    const float* th1   = (const float*)d_in[1];
    const float* W1    = (const float*)d_in[2];
    const float* b1    = (const float*)d_in[3];
    const float* gamma = (const float*)d_in[4];
    const float* beta  = (const float*)d_in[5];
    const float* th2   = (const float*)d_in[6];
    const float* W2    = (const float*)d_in[7];
    const float* b2    = (const float*)d_in[8];
    float* out = (float*)d_out;

    const int B = in_sizes[0] / FT;   // 8192
    dim3 grid(B / 4), block(256);     // 1 wave per batch
    hipLaunchKernelGGL(scorer_kernel, grid, block, 0, stream,
                       x, th1, W1, b1, gamma, beta, th2, W2, b2, out);
}